// Round 9
// baseline (401.342 us; speedup 1.0000x reference)
//
#include <hip/hip_runtime.h>
#include <hip/hip_bf16.h>

typedef int i32x4 __attribute__((ext_vector_type(4)));

#define N_TOKENS 32768
#define N_CODES 4096
#define DIM 1280
#define NT 10            // K-tiles of 128 i8

__device__ __forceinline__ void load_lds16(const void* g, void* l) {
    __builtin_amdgcn_global_load_lds(
        (const __attribute__((address_space(1))) unsigned int*)g,
        (__attribute__((address_space(3))) unsigned int*)l,
        16, 0, 0);
}

// ---------------------------------------------------------------------------
// Kernel 0: per-row symmetric int8 quantize (RNE), X and E fused. Verified
// r5-r8: exact-int dot => score err sigma ~3.4e-4; refine thr 3e-3 ~ 9 sigma.
// ---------------------------------------------------------------------------
__global__ __launch_bounds__(256) void quantize_i8_kernel(
    const float* __restrict__ X, const float* __restrict__ E,
    signed char* __restrict__ Xq, signed char* __restrict__ Eq,
    float* __restrict__ sxs, float* __restrict__ ses)
{
    int row = blockIdx.x * 4 + (threadIdx.x >> 6);
    const float* src;
    signed char* dst;
    float* scale;
    if (row < N_TOKENS) {
        src = X + (size_t)row * DIM; dst = Xq + (size_t)row * DIM; scale = sxs + row;
    } else {
        int r = row - N_TOKENS;
        if (r >= N_CODES) return;
        src = E + (size_t)r * DIM; dst = Eq + (size_t)r * DIM; scale = ses + r;
    }
    int lane = threadIdx.x & 63;
    const float4* s4 = (const float4*)src;
    float4 v[5];
    float amax = 0.f;
    #pragma unroll
    for (int j = 0; j < 5; ++j) {
        v[j] = s4[j * 64 + lane];
        amax = fmaxf(amax, fmaxf(fmaxf(fabsf(v[j].x), fabsf(v[j].y)),
                                 fmaxf(fabsf(v[j].z), fabsf(v[j].w))));
    }
    #pragma unroll
    for (int d = 1; d < 64; d <<= 1) amax = fmaxf(amax, __shfl_xor(amax, d));
    amax = fmaxf(amax, 1e-20f);
    float inv = 127.0f / amax;
    int* d4 = (int*)dst;
    #pragma unroll
    for (int j = 0; j < 5; ++j) {
        int q0 = (int)rintf(v[j].x * inv), q1 = (int)rintf(v[j].y * inv);
        int q2 = (int)rintf(v[j].z * inv), q3 = (int)rintf(v[j].w * inv);
        d4[j * 64 + lane] = (q0 & 0xFF) | ((q1 & 0xFF) << 8) |
                            ((q2 & 0xFF) << 16) | ((q3 & 0xFF) << 24);
    }
    if (lane == 0) *scale = amax * (1.0f / 127.0f);
}

// ---------------------------------------------------------------------------
// Kernel 1: i8 GEMM 256x256, 8 waves (2M x 4N, wave tile 128x64), BK=128,
// 8-phase-style schedule: 4 phases/tile x 16 MFMA, half-tile staging with
// counted vmcnt(8) at mid-tile and tile-end only.
// LDS per buffer: A [kk:2][row:256][64B] (32KB) | B same (32KB); 2 buffers.
// Swizzle: LDS chunk c of row r stores source chunk c ^ ((r>>1)&3) within
// the 64B half-row (2-way residual bank aliasing = free). Verified algebra:
// reader (lr,g) uses chunk g^((lr>>1)&3); staged slot f=(4r+c) came from
// source chunk (f&3)^((f>>3)&3) = c^((r>>1)&3) -> roundtrip cp = g.
// Half H = 2*tile + kk. STAGING LEDGER (4 loads/thread/half):
//   prologue: issue H0,H1,H2 (12) -> vmcnt(8) certifies H0 -> barrier.
//   tile t: P0 reads kk0 (=H2t), issues H=2t+3 loads 0-1 (other buffer, kk1)
//           P1 reads kk0, issues H=2t+3 loads 2-3; END: vmcnt(8) certifies
//               H=2t+1 (outstanding = H2t+2, H2t+3 = 8)
//           P2 reads kk1 (=H2t+1), issues H=2t+4 loads 0-1 (THIS buffer kk0:
//               safe, kk0 reads finished at P1/P2 barrier)
//           P3 reads kk1, issues H=2t+4 loads 2-3; END: vmcnt(8) certifies
//               H=2t+2 (outstanding = H2t+3, H2t+4 = 8)
//   tail: t=8 issues only H19 (P0/P1); ends vmcnt(8)/vmcnt(4).
//         t=9 issues nothing; ends vmcnt(0)/none.
// Each phase: {ds_read frags | 2 staging issues} -> s_barrier -> setprio(1)
// 16 MFMA setprio(0) -> [vmcnt] -> s_barrier -> sched_barrier(0).
// ---------------------------------------------------------------------------
__global__ __launch_bounds__(512, 2) void gemm_argmax_kernel(
    const signed char* __restrict__ Xq, const signed char* __restrict__ Eq,
    const float* __restrict__ sx, const float* __restrict__ se,
    unsigned* __restrict__ pkeys)
{
    __shared__ __align__(16) char lds[131072];   // 128 KB

    int bid = blockIdx.x;
    // bijective XCD swizzle: 2048 blocks, 256/XCD (rb 128 x cb0 2 per XCD)
    int swz = (bid & 7) * 256 + (bid >> 3);
    int cb0 = swz >> 7, rb = swz & 127;
    int row0 = rb << 8, col0 = cb0 << 8;

    int tid = threadIdx.x;
    int wid = tid >> 6, lane = tid & 63;
    int wm = wid >> 2, wn = wid & 3;          // 2x4 wave grid
    int lr = lane & 15, g = lane >> 4;

    // fragment read offsets (lane-constant)
    int chunk = g ^ ((lr >> 1) & 3);
    int aoff = ((wm << 7) + lr) * 64 + (chunk << 4);            // + m*1024 + kk*16384 + buf
    int boff = 32768 + ((wn << 6) + lr) * 64 + (chunk << 4);    // + n*1024 + kk*16384 + buf

    // staging constants: slots f and f+512 for each operand
    int f0 = tid, f1 = tid + 512;
    int cp0 = ((f0 & 3) ^ ((f0 >> 3) & 3)) << 4;
    int cp1 = ((f1 & 3) ^ ((f1 >> 3) & 3)) << 4;
    const signed char* sA0 = Xq + (size_t)(row0 + (f0 >> 2)) * DIM + cp0;
    const signed char* sA1 = Xq + (size_t)(row0 + (f1 >> 2)) * DIM + cp1;
    const signed char* sB0 = Eq + (size_t)(col0 + (f0 >> 2)) * DIM + cp0;
    const signed char* sB1 = Eq + (size_t)(col0 + (f1 >> 2)) * DIM + cp1;
    int dA0 = f0 << 4, dA1 = f1 << 4;
    int dB0 = 32768 + (f0 << 4), dB1 = 32768 + (f1 << 4);

    i32x4 acc[8][4] = {};

    // part 0 = A slots, part 1 = B slots; H = 2*tile + kk
    auto STAGE = [&](int H, int part) {
        int dbase = ((H >> 1) & 1) * 65536 + (H & 1) * 16384;
        int goff = H << 6;
        if (part == 0) {
            load_lds16(sA0 + goff, lds + dbase + dA0);
            load_lds16(sA1 + goff, lds + dbase + dA1);
        } else {
            load_lds16(sB0 + goff, lds + dbase + dB0);
            load_lds16(sB1 + goff, lds + dbase + dB1);
        }
    };

    STAGE(0, 0); STAGE(0, 1); STAGE(1, 0); STAGE(1, 1); STAGE(2, 0); STAGE(2, 1);
    asm volatile("s_waitcnt vmcnt(8)" ::: "memory");
    __builtin_amdgcn_s_barrier();
    __builtin_amdgcn_sched_barrier(0);

    i32x4 a[4], b[4];
    for (int t = 0; t < NT; ++t) {
        int bufb = (t & 1) * 65536;
        #pragma unroll
        for (int P = 0; P < 4; ++P) {
            const int kk = P >> 1, mb = (P & 1) * 4;
            const char* base = lds + bufb + kk * 16384;
            if ((P & 1) == 0) {
                #pragma unroll
                for (int n = 0; n < 4; ++n)
                    b[n] = *(const i32x4*)(base + boff + (n << 10));
            }
            #pragma unroll
            for (int j = 0; j < 4; ++j)
                a[j] = *(const i32x4*)(base + aoff + ((mb + j) << 10));
            // staging issues (2 per phase)
            if (P < 2) { if (t <= 8) STAGE(2 * t + 3, P); }
            else       { if (t <= 7) STAGE(2 * t + 4, P - 2); }
            __builtin_amdgcn_s_barrier();
            __builtin_amdgcn_s_setprio(1);
            #pragma unroll
            for (int j = 0; j < 4; ++j)
                #pragma unroll
                for (int n = 0; n < 4; ++n)
                    acc[mb + j][n] = __builtin_amdgcn_mfma_i32_16x16x64_i8(
                        a[j], b[n], acc[mb + j][n], 0, 0, 0);
            __builtin_amdgcn_s_setprio(0);
            if (P == 1) {
                if (t <= 8) { asm volatile("s_waitcnt vmcnt(8)" ::: "memory"); }
                else        { asm volatile("s_waitcnt vmcnt(0)" ::: "memory"); }
            } else if (P == 3) {
                if (t <= 7)      { asm volatile("s_waitcnt vmcnt(8)" ::: "memory"); }
                else if (t == 8) { asm volatile("s_waitcnt vmcnt(4)" ::: "memory"); }
            }
            __builtin_amdgcn_s_barrier();
            __builtin_amdgcn_sched_barrier(0);
        }
    }
    __syncthreads();   // drain; LDS reused for epilogue merge

    // ---- dequant + fused top-2 argmax epilogue (r4 geometry + r6 dequant) ----
    // C/D frag layout (dtype-independent): col = lr, row = g*4 + r.
    float se_l[4];
    #pragma unroll
    for (int n = 0; n < 4; ++n)
        se_l[n] = se[col0 + (wn << 6) + (n << 4) + lr];

    uint2* lk2 = (uint2*)lds;   // [256 rows][4 wn]
    #pragma unroll
    for (int m = 0; m < 8; ++m) {
        #pragma unroll
        for (int r = 0; r < 4; ++r) {
            int row = (wm << 7) + (m << 4) + (g << 2) + r;   // 0..255
            float fx = sx[row0 + row];
            unsigned b1 = 0, b2 = 0;
            #pragma unroll
            for (int n = 0; n < 4; ++n) {
                float s = (float)acc[m][n][r] * (fx * se_l[n]);
                int cib = ((wn & 1) << 6) + (n << 4) + lr;   // col in 128-block
                unsigned u = __float_as_uint(s);
                u = (u & 0x80000000u) ? ~u : (u | 0x80000000u);
                unsigned key = (u & 0xFFFFFF80u) | (unsigned)(127 - cib);
                if (key > b1) { b2 = b1; b1 = key; }
                else if (key > b2) b2 = key;
            }
            #pragma unroll
            for (int d = 1; d < 16; d <<= 1) {   // merge across 16 lanes (lr)
                unsigned o1 = __shfl_xor(b1, d), o2 = __shfl_xor(b2, d);
                if (o1 > b1) { b2 = (b1 > o2) ? b1 : o2; b1 = o1; }
                else if (o1 > b2) b2 = o1;
            }
            if (lr == 0) {
                uint2 v; v.x = b1; v.y = b2;
                lk2[(row << 2) + wn] = v;
            }
        }
    }
    __syncthreads();
    {
        int row = tid >> 1, h = tid & 1;
        uint2 p0 = lk2[(row << 2) + (h << 1)];
        uint2 p1 = lk2[(row << 2) + (h << 1) + 1];
        unsigned b1 = p0.x, b2 = p0.y;
        if (p1.x > b1) { b2 = (b1 > p1.y) ? b1 : p1.y; b1 = p1.x; }
        else if (p1.x > b2) b2 = p1.x;
        uint2 out; out.x = b1; out.y = b2;
        *(uint2*)&pkeys[((size_t)(row0 + row) << 6) + (((cb0 << 1) + h) << 1)] = out;
    }
}

// ---------------------------------------------------------------------------
// Kernel 2: fused exact fp64 refine + gather + loss partial. One wave/token.
// Threshold 3e-3 (~9 sigma i8 noise). Verified r5-r8.
// ---------------------------------------------------------------------------
__global__ __launch_bounds__(64) void refine_gather_kernel(
    const float* __restrict__ X, const float* __restrict__ E,
    const unsigned* __restrict__ pkeys, float* __restrict__ outq,
    float* __restrict__ outidx, float* __restrict__ sums)
{
    int token = blockIdx.x;
    int lane = threadIdx.x;
    unsigned k = pkeys[((size_t)token << 6) + lane];
    unsigned m = k & 0xFFFFFF80u;
    float s = __uint_as_float((m & 0x80000000u) ? (m & 0x7FFFFFFFu) : ~m);
    float smax = s;
    #pragma unroll
    for (int d = 1; d < 64; d <<= 1) smax = fmaxf(smax, __shfl_xor(smax, d));
    bool cand = s >= smax - 3e-3f;
    unsigned long long ball = __ballot(cand);

    const float4* x4 = (const float4*)(X + (size_t)token * DIM);
    float4 xv[5];
    #pragma unroll
    for (int j = 0; j < 5; ++j) xv[j] = x4[j * 64 + lane];

    double best_s = -1.0e300;
    int best_i = 0x7FFFFFFF;
    while (ball) {
        int src = __ffsll(ball) - 1;
        ball &= ball - 1;
        unsigned ck = __shfl(k, src);
        int cidx = ((src >> 1) << 7) + (127 - (int)(ck & 127u));
        const float4* e4 = (const float4*)(E + (size_t)cidx * DIM);
        double d = 0.0, ee = 0.0;
        #pragma unroll
        for (int j = 0; j < 5; ++j) {
            float4 ev = e4[j * 64 + lane];
            d += (double)xv[j].x * (double)ev.x + (double)xv[j].y * (double)ev.y
               + (double)xv[j].z * (double)ev.z + (double)xv[j].w * (double)ev.w;
            ee += (double)ev.x * (double)ev.x + (double)ev.y * (double)ev.y
                + (double)ev.z * (double)ev.z + (double)ev.w * (double)ev.w;
        }
        #pragma unroll
        for (int dd = 1; dd < 64; dd <<= 1) {
            d += __shfl_xor(d, dd);
            ee += __shfl_xor(ee, dd);
        }
        double sc = 2.0 * d - ee;
        if (sc > best_s || (sc == best_s && cidx < best_i)) { best_s = sc; best_i = cidx; }
    }

    const float4* e4 = (const float4*)(E + (size_t)best_i * DIM);
    float4* o4 = (float4*)(outq + (size_t)token * DIM);
    float local = 0.0f;
    #pragma unroll
    for (int j = 0; j < 5; ++j) {
        float4 q = e4[j * 64 + lane];
        o4[j * 64 + lane] = q;
        float dx = xv[j].x - q.x, dy = xv[j].y - q.y;
        float dz = xv[j].z - q.z, dw = xv[j].w - q.w;
        local += dx * dx + dy * dy + dz * dz + dw * dw;
    }
    #pragma unroll
    for (int d = 1; d < 64; d <<= 1) local += __shfl_xor(local, d);
    if (lane == 0) {
        sums[token] = local;
        outidx[token] = (float)best_i;
    }
}

// ---------------------------------------------------------------------------
// Kernel 3: deterministic final loss reduction (fixed tree).
// ---------------------------------------------------------------------------
__global__ __launch_bounds__(256) void loss_kernel(
    const float* __restrict__ sums, float* __restrict__ out_loss)
{
    __shared__ double red[256];
    int t = threadIdx.x;
    double s = 0.0;
    for (int i = t; i < N_TOKENS; i += 256) s += (double)sums[i];
    red[t] = s;
    __syncthreads();
    for (int off = 128; off > 0; off >>= 1) {
        if (t < off) red[t] += red[t + off];
        __syncthreads();
    }
    if (t == 0) out_loss[0] = (float)(red[0] / (double)((size_t)N_TOKENS * DIM));
}

extern "C" void kernel_launch(void* const* d_in, const int* in_sizes, int n_in,
                              void* d_out, int out_size, void* d_ws, size_t ws_size,
                              hipStream_t stream)
{
    const float* X = (const float*)d_in[0];   // (32768, 1280) fp32
    const float* E = (const float*)d_in[1];   // (4096, 1280) fp32

    float* outq = (float*)d_out;                       // (32768,1280)
    float* outidx = outq + (size_t)N_TOKENS * DIM;     // (32768,) as float
    float* outloss = outidx + N_TOKENS;                // scalar

    // i8 temps + scales inside outq region (47.3 MB of 167.9 MB); consumed
    // by GEMM, then fully overwritten by refine_gather in-stream.
    signed char* Xq = (signed char*)d_out;                        // 41.9 MB
    signed char* Eq = Xq + (size_t)N_TOKENS * DIM;                // 5.2 MB
    float* sxs = (float*)(Eq + (size_t)N_CODES * DIM);            // 128 KB
    float* ses = sxs + N_TOKENS;                                  // 16 KB

    unsigned* pkeys = (unsigned*)d_ws;                            // 8 MB
    float* sums = (float*)((char*)d_ws + (size_t)N_TOKENS * 64 * sizeof(unsigned));

    quantize_i8_kernel<<<dim3((N_TOKENS + N_CODES) / 4), dim3(256), 0, stream>>>(
        X, E, Xq, Eq, sxs, ses);
    gemm_argmax_kernel<<<dim3(2048), dim3(512), 0, stream>>>(Xq, Eq, sxs, ses, pkeys);
    refine_gather_kernel<<<dim3(N_TOKENS), dim3(64), 0, stream>>>(X, E, pkeys, outq, outidx, sums);
    loss_kernel<<<dim3(1), dim3(256), 0, stream>>>(sums, outloss);
}